// Round 1
// baseline (1114.491 us; speedup 1.0000x reference)
//
#include <hip/hip_runtime.h>
#include <hip/hip_bf16.h>

// B=2, S=4096, E=1024 attention with QKV projections.
// Plan: 3 bf16 MFMA GEMMs (cast fp32->bf16 during LDS staging) producing
// qb[8192x1024], kb[8192x1024] (row-major) and vt[b][1024][4096] (V transposed,
// obtained by swapping A/B roles), then a flash-attention kernel
// (Q-tile 32, KV-tile 64, online softmax, D=1024 split 128-wide across 8 waves).

typedef __bf16 bf16_t;
typedef __bf16 bf16x8 __attribute__((ext_vector_type(8)));
typedef float f32x4 __attribute__((ext_vector_type(4)));

__device__ __forceinline__ f32x4 mfma_bf16(bf16x8 a, bf16x8 b, f32x4 c) {
  return __builtin_amdgcn_mfma_f32_16x16x32_bf16(a, b, c, 0, 0, 0);
}

// ---------------- GEMM: C[m,n] = sum_k A[m,k]*B[n,k] + bias -----------------
// A: [M x K] fp32, B: [N x K] fp32 (B-transposed layout), C: bf16.
// bias_per_row=0: bias[n] (q/k projections); =1: bias[m] (v projection, A=W).
// vt_mode=1: write C to vt layout: off = (n/4096)*E*S + m*4096 + (n%4096).
#define GBM 128
#define GBN 128
#define GBK 64
#define GLD 72  // LDS row stride in bf16 elems (64 + 8 pad, keeps 16B align)

__global__ __launch_bounds__(256) void gemm_bt_f32in_bf16out(
    const float* __restrict__ A, const float* __restrict__ B,
    const float* __restrict__ bias, bf16_t* __restrict__ C,
    int M, int N, int K, int bias_per_row, int vt_mode) {
  __shared__ bf16_t sA[GBM * GLD];
  __shared__ bf16_t sB[GBN * GLD];

  const int n0 = blockIdx.x * GBN;
  const int m0 = blockIdx.y * GBM;
  const int tid = threadIdx.x;
  const int wave = tid >> 6, lane = tid & 63;
  const int quad = lane >> 4, l15 = lane & 15;
  const int wm = wave >> 1, wn = wave & 1;

  // staging assignment: thread = (row 0..127, half 0..1), 8 float4 each
  const int sr = tid >> 1;
  const int sh = tid & 1;
  const float* Ap = A + (size_t)(m0 + sr) * K + sh * 32;
  const float* Bp = B + (size_t)(n0 + sr) * K + sh * 32;
  bf16_t* sAp = &sA[sr * GLD + sh * 32];
  bf16_t* sBp = &sB[sr * GLD + sh * 32];

  f32x4 acc[4][4] = {};

  for (int k0 = 0; k0 < K; k0 += GBK) {
    __syncthreads();
#pragma unroll
    for (int i = 0; i < 8; i++) {
      float4 a = *(const float4*)(Ap + k0 + i * 4);
      sAp[i * 4 + 0] = (bf16_t)a.x; sAp[i * 4 + 1] = (bf16_t)a.y;
      sAp[i * 4 + 2] = (bf16_t)a.z; sAp[i * 4 + 3] = (bf16_t)a.w;
      float4 b = *(const float4*)(Bp + k0 + i * 4);
      sBp[i * 4 + 0] = (bf16_t)b.x; sBp[i * 4 + 1] = (bf16_t)b.y;
      sBp[i * 4 + 2] = (bf16_t)b.z; sBp[i * 4 + 3] = (bf16_t)b.w;
    }
    __syncthreads();
#pragma unroll
    for (int ks = 0; ks < 2; ks++) {
      bf16x8 af[4], bfr[4];
#pragma unroll
      for (int mi = 0; mi < 4; mi++)
        af[mi] = *(const bf16x8*)&sA[(wm * 64 + mi * 16 + l15) * GLD + ks * 32 + quad * 8];
#pragma unroll
      for (int ni = 0; ni < 4; ni++)
        bfr[ni] = *(const bf16x8*)&sB[(wn * 64 + ni * 16 + l15) * GLD + ks * 32 + quad * 8];
#pragma unroll
      for (int mi = 0; mi < 4; mi++)
#pragma unroll
        for (int ni = 0; ni < 4; ni++)
          acc[mi][ni] = mfma_bf16(af[mi], bfr[ni], acc[mi][ni]);
    }
  }

  // epilogue: C/D layout col=lane&15, row=quad*4+reg (m89/m91-verified)
#pragma unroll
  for (int mi = 0; mi < 4; mi++) {
#pragma unroll
    for (int ni = 0; ni < 4; ni++) {
      const int gm0 = m0 + wm * 64 + mi * 16 + quad * 4;
      const int gn = n0 + wn * 64 + ni * 16 + l15;
      const float bc = bias_per_row ? 0.f : bias[gn];
#pragma unroll
      for (int r = 0; r < 4; r++) {
        const int gm = gm0 + r;
        float v = acc[mi][ni][r] + (bias_per_row ? bias[gm] : bc);
        if (vt_mode) {
          const int bb = gn >> 12;           // batch (tiles never cross 4096)
          const int s = gn & 4095;
          C[(size_t)bb * (1024 * 4096) + (size_t)gm * 4096 + s] = (bf16_t)v;
        } else {
          C[(size_t)gm * N + gn] = (bf16_t)v;
        }
      }
    }
  }
}

// ---------------- Flash attention -----------------
// Per workgroup (512 thr = 8 waves): batch b, 32 query rows.
// S-phase: wave (smi=w>>2, sni=w&3) computes S-tile[smi*16..+16, sni*16..+16]
//   over K=1024 via LDS-staged q/k chunks (EC=256).
// Softmax: online (m, l, alpha) in LDS; P -> LDS bf16.
// PV: wave w owns D-slice [w*128, +128); B-frags straight from global vt
//   (L2/L3-resident, 16B/lane, lines fully consumed across quads).
#define QT 32
#define KVT 64
#define EC 256
#define LQS 264  // staging row stride (256 + 8), 16B aligned
#define LPP 72   // P row stride (64 + 8)
#define SSZ 4096
#define EDIM 1024

__global__ __launch_bounds__(512) void flash_attn(
    const bf16_t* __restrict__ qb, const bf16_t* __restrict__ kb,
    const bf16_t* __restrict__ vt, const int* __restrict__ mask,
    float* __restrict__ out) {
  __shared__ bf16_t qs[QT * LQS];
  __shared__ bf16_t ksh[KVT * LQS];
  __shared__ bf16_t Ps[QT * LPP];
  __shared__ float red_max[4][QT];
  __shared__ float red_sum[4][QT];
  __shared__ float m_s[QT], l_s[QT], al_s[QT];

  const int b = blockIdx.x >> 7;           // 128 q-tiles per batch
  const int q0 = (blockIdx.x & 127) * QT;
  const int tid = threadIdx.x;
  const int wave = tid >> 6, lane = tid & 63;
  const int quad = lane >> 4, l15 = lane & 15;
  const int smi = wave >> 2, sni = wave & 3;

  if (tid < QT) { m_s[tid] = -__builtin_inff(); l_s[tid] = 0.f; }

  f32x4 o_acc[2][8] = {};

  const bf16_t* qbase = qb + (size_t)(b * SSZ + q0) * EDIM;
  const bf16_t* kbase = kb + (size_t)b * SSZ * EDIM;
  const bf16_t* vbase = vt + (size_t)b * EDIM * SSZ;

  for (int kv0 = 0; kv0 < SSZ; kv0 += KVT) {
    f32x4 s_acc = {0.f, 0.f, 0.f, 0.f};
    for (int e0 = 0; e0 < EDIM; e0 += EC) {
      __syncthreads();
      // stage q-chunk: 32 rows x 256 = 1024 x 8-elem segs, 2 per thread
#pragma unroll
      for (int j = 0; j < 2; j++) {
        const int idx = tid + j * 512;
        const int r = idx >> 5, sg = idx & 31;
        *(bf16x8*)&qs[r * LQS + sg * 8] =
            *(const bf16x8*)&qbase[(size_t)r * EDIM + e0 + sg * 8];
      }
      // stage k-chunk: 64 rows x 256 = 2048 segs, 4 per thread
#pragma unroll
      for (int j = 0; j < 4; j++) {
        const int idx = tid + j * 512;
        const int r = idx >> 5, sg = idx & 31;
        *(bf16x8*)&ksh[r * LQS + sg * 8] =
            *(const bf16x8*)&kbase[(size_t)(kv0 + r) * EDIM + e0 + sg * 8];
      }
      __syncthreads();
#pragma unroll
      for (int kk = 0; kk < 8; kk++) {
        bf16x8 aq = *(const bf16x8*)&qs[(smi * 16 + l15) * LQS + kk * 32 + quad * 8];
        bf16x8 bk = *(const bf16x8*)&ksh[(sni * 16 + l15) * LQS + kk * 32 + quad * 8];
        s_acc = mfma_bf16(aq, bk, s_acc);
      }
    }
    // scale + mask (True -> -1e9, matching reference NINF)
    const int qrow0 = q0 + smi * 16 + quad * 4;
    const int kvc = kv0 + sni * 16 + l15;
    float sv[4];
#pragma unroll
    for (int r = 0; r < 4; r++) {
      const float x = s_acc[r] * 0.03125f;  // 1/sqrt(1024)
      sv[r] = mask[(size_t)(qrow0 + r) * SSZ + kvc] ? -1.0e9f : x;
    }
    // within-wave row max (16 lanes of each quad hold one row's 16 cols)
#pragma unroll
    for (int r = 0; r < 4; r++) {
      float v = sv[r];
      v = fmaxf(v, __shfl_xor(v, 1));
      v = fmaxf(v, __shfl_xor(v, 2));
      v = fmaxf(v, __shfl_xor(v, 4));
      v = fmaxf(v, __shfl_xor(v, 8));
      if (l15 == 0) red_max[sni][smi * 16 + quad * 4 + r] = v;
    }
    __syncthreads();
    if (tid < QT) {
      const float tm = fmaxf(fmaxf(red_max[0][tid], red_max[1][tid]),
                             fmaxf(red_max[2][tid], red_max[3][tid]));
      const float mo = m_s[tid];
      const float mn = fmaxf(mo, tm);
      const float al = __expf(mo - mn);  // first tile: exp(-inf)=0
      m_s[tid] = mn; al_s[tid] = al; l_s[tid] *= al;
    }
    __syncthreads();
    // P = exp(s - m); write bf16 P tile; per-row partial sums
#pragma unroll
    for (int r = 0; r < 4; r++) {
      const int row = smi * 16 + quad * 4 + r;
      const float p = __expf(sv[r] - m_s[row]);
      Ps[row * LPP + sni * 16 + l15] = (bf16_t)p;
      float v = p;
      v += __shfl_xor(v, 1); v += __shfl_xor(v, 2);
      v += __shfl_xor(v, 4); v += __shfl_xor(v, 8);
      if (l15 == 0) red_sum[sni][row] = v;
    }
    __syncthreads();
    if (tid < QT)
      l_s[tid] += red_sum[0][tid] + red_sum[1][tid] +
                  red_sum[2][tid] + red_sum[3][tid];
    // rescale O accumulator by alpha (al_s stable since stats barrier)
#pragma unroll
    for (int mt = 0; mt < 2; mt++) {
      float al[4];
#pragma unroll
      for (int r = 0; r < 4; r++) al[r] = al_s[mt * 16 + quad * 4 + r];
#pragma unroll
      for (int nt = 0; nt < 8; nt++)
#pragma unroll
        for (int r = 0; r < 4; r++) o_acc[mt][nt][r] *= al[r];
    }
    // PV: O[32 x 128-slice] += P[32x64] @ V[64 x slice]
#pragma unroll
    for (int ksv = 0; ksv < 2; ksv++) {
      bf16x8 pa[2];
#pragma unroll
      for (int mt = 0; mt < 2; mt++)
        pa[mt] = *(const bf16x8*)&Ps[(mt * 16 + l15) * LPP + ksv * 32 + quad * 8];
#pragma unroll
      for (int nt = 0; nt < 8; nt++) {
        const int n = wave * 128 + nt * 16 + l15;
        bf16x8 vb = *(const bf16x8*)&vbase[(size_t)n * SSZ + kv0 + ksv * 32 + quad * 8];
#pragma unroll
        for (int mt = 0; mt < 2; mt++)
          o_acc[mt][nt] = mfma_bf16(pa[mt], vb, o_acc[mt][nt]);
      }
    }
  }
  __syncthreads();  // l_s final before epilogue reads
#pragma unroll
  for (int mt = 0; mt < 2; mt++) {
    float rl[4];
#pragma unroll
    for (int r = 0; r < 4; r++) rl[r] = 1.0f / l_s[mt * 16 + quad * 4 + r];
#pragma unroll
    for (int nt = 0; nt < 8; nt++) {
#pragma unroll
      for (int r = 0; r < 4; r++) {
        const int row = mt * 16 + quad * 4 + r;
        out[(size_t)(b * SSZ + q0 + row) * EDIM + wave * 128 + nt * 16 + l15] =
            o_acc[mt][nt][r] * rl[r];
      }
    }
  }
}

extern "C" void kernel_launch(void* const* d_in, const int* in_sizes, int n_in,
                              void* d_out, int out_size, void* d_ws, size_t ws_size,
                              hipStream_t stream) {
  const float* query = (const float*)d_in[0];
  const float* key_  = (const float*)d_in[1];
  const float* value = (const float*)d_in[2];
  const int* mask    = (const int*)d_in[3];
  const float* Wq = (const float*)d_in[4];
  const float* bq = (const float*)d_in[5];
  const float* Wk = (const float*)d_in[6];
  const float* bk = (const float*)d_in[7];
  const float* Wv = (const float*)d_in[8];
  const float* bv = (const float*)d_in[9];
  float* out = (float*)d_out;

  // workspace: qb (16MB) | kb (16MB) | vt (16MB)  -- all bf16
  bf16_t* qb = (bf16_t*)d_ws;
  bf16_t* kb = qb + (size_t)8192 * 1024;
  bf16_t* vt = kb + (size_t)8192 * 1024;

  const dim3 blk(256);
  // q = query @ Wq^T + bq  -> qb [8192 x 1024]
  gemm_bt_f32in_bf16out<<<dim3(1024 / GBN, 8192 / GBM), blk, 0, stream>>>(
      query, Wq, bq, qb, 8192, 1024, 1024, 0, 0);
  // k = key @ Wk^T + bk -> kb
  gemm_bt_f32in_bf16out<<<dim3(1024 / GBN, 8192 / GBM), blk, 0, stream>>>(
      key_, Wk, bk, kb, 8192, 1024, 1024, 0, 0);
  // v^T: A=Wv [1024xK], B=value [8192xK], bias per-row -> vt[b][e][s]
  gemm_bt_f32in_bf16out<<<dim3(8192 / GBN, 1024 / GBM), blk, 0, stream>>>(
      Wv, value, bv, vt, 1024, 8192, 1024, 1, 1);
  // flash attention: 256 workgroups (2 batches x 128 q-tiles)
  flash_attn<<<dim3(256), dim3(512), 0, stream>>>(qb, kb, vt, mask, out);
}